// Round 2
// baseline (253.998 us; speedup 1.0000x reference)
//
#include <hip/hip_runtime.h>

typedef __attribute__((ext_vector_type(8))) _Float16 f16x8;
typedef __attribute__((ext_vector_type(2))) __fp16   fp16x2;  // cvt_pkrtz return type
typedef __attribute__((ext_vector_type(4))) float    f32x4;

#define TT 16384
#define KD 1024
#define ND 3072
#define NE 16

#define BM 128
#define BN 128
#define BK 64
#define NSTEP (KD / BK)   // 16
#define NTHREADS 256
#define ROWB (BK * 2)     // 128 bytes per LDS row (fp16)

// XOR swizzle: spreads same-column reads of 16 consecutive rows across banks.
__device__ __forceinline__ int swz(int row, int kbyte) {
    return row * ROWB + (kbyte ^ ((row & 7) << 4));
}

__device__ __forceinline__ int find_expert(const void* cntp, int row0) {
    // JAX default config demotes int64 -> int32; detect which layout we got.
    const int* w = (const int*)cntp;
    int oddsum = 0;
    #pragma unroll
    for (int i = 1; i < 16; i += 2) oddsum |= w[i];
    int e = 0;
    long long cum = 0;
    if (oddsum == 0) {  // int64 counts (high words all zero)
        const long long* c = (const long long*)cntp;
        #pragma unroll
        for (int i = 0; i < NE; ++i) { if ((long long)row0 >= cum) e = i; cum += c[i]; }
    } else {            // int32 counts
        #pragma unroll
        for (int i = 0; i < NE; ++i) { if ((long long)row0 >= cum) e = i; cum += w[i]; }
    }
    return e;
}

__launch_bounds__(NTHREADS, 2)
__global__ void grouped_gemm_f16(const float* __restrict__ A,
                                 const void* __restrict__ cnt,
                                 const float* __restrict__ W,
                                 const float* __restrict__ bias,
                                 float* __restrict__ Y) {
    __shared__ __align__(16) char ldsbuf[2][2][BM * ROWB];  // [dbuf][A/B], 64 KiB total

    const int bid = blockIdx.x;
    const int mt = bid / (ND / BN);
    const int nt = bid % (ND / BN);
    const int row0 = mt * BM;
    const int col0 = nt * BN;

    const int e = find_expert(cnt, row0);
    const float* We = W + (size_t)e * ND * KD;

    const int tid = threadIdx.x;
    const int lane = tid & 63;
    const int w = tid >> 6;   // wave 0..3
    const int wr = w >> 1;    // 0..1 (M)
    const int wc = w & 1;     // 0..1 (N)
    const int lr = lane & 15;
    const int lk = lane >> 4;

    // Staging decomposition: tile = 128 rows x 64 k = 1024 chunks of 8 floats.
    // 256 threads x 4 chunks. Consecutive tids walk k-first (coalesced 256B/row).
    int soff[4];          // swizzled LDS byte offset per chunk
    size_t aoff[4], boff[4];
    #pragma unroll
    for (int c = 0; c < 4; ++c) {
        int q = c * NTHREADS + tid;
        int r = q >> 3;
        int kb = (q & 7) * 8;
        soff[c] = swz(r, kb * 2);
        aoff[c] = (size_t)(row0 + r) * KD + kb;
        boff[c] = (size_t)(col0 + r) * KD + kb;
    }

    f32x4 ra[4][2], rbuf[4][2];

    auto load_regs = [&](int ks) {
        const int k0 = ks * BK;
        #pragma unroll
        for (int c = 0; c < 4; ++c) {
            const float* ap = A + aoff[c] + k0;
            ra[c][0] = *(const f32x4*)ap;
            ra[c][1] = *(const f32x4*)(ap + 4);
            const float* bp = We + boff[c] + k0;
            rbuf[c][0] = *(const f32x4*)bp;
            rbuf[c][1] = *(const f32x4*)(bp + 4);
        }
    };

    auto write_lds = [&](int buf) {
        #pragma unroll
        for (int c = 0; c < 4; ++c) {
            union { f16x8 v; fp16x2 h[4]; } ua, ub;
            ua.h[0] = __builtin_amdgcn_cvt_pkrtz(ra[c][0][0], ra[c][0][1]);
            ua.h[1] = __builtin_amdgcn_cvt_pkrtz(ra[c][0][2], ra[c][0][3]);
            ua.h[2] = __builtin_amdgcn_cvt_pkrtz(ra[c][1][0], ra[c][1][1]);
            ua.h[3] = __builtin_amdgcn_cvt_pkrtz(ra[c][1][2], ra[c][1][3]);
            ub.h[0] = __builtin_amdgcn_cvt_pkrtz(rbuf[c][0][0], rbuf[c][0][1]);
            ub.h[1] = __builtin_amdgcn_cvt_pkrtz(rbuf[c][0][2], rbuf[c][0][3]);
            ub.h[2] = __builtin_amdgcn_cvt_pkrtz(rbuf[c][1][0], rbuf[c][1][1]);
            ub.h[3] = __builtin_amdgcn_cvt_pkrtz(rbuf[c][1][2], rbuf[c][1][3]);
            *(f16x8*)&ldsbuf[buf][0][soff[c]] = ua.v;
            *(f16x8*)&ldsbuf[buf][1][soff[c]] = ub.v;
        }
    };

    f32x4 acc[4][4] = {};

    load_regs(0);
    write_lds(0);
    __syncthreads();

    int cur = 0;
    for (int ks = 0; ks < NSTEP; ++ks) {
        if (ks + 1 < NSTEP) load_regs(ks + 1);   // prefetch next K-tile into regs

        const char* As = ldsbuf[cur][0];
        const char* Bs = ldsbuf[cur][1];
        #pragma unroll
        for (int kk = 0; kk < 2; ++kk) {          // two K=32 sub-steps
            f16x8 af[4], bf[4];
            #pragma unroll
            for (int m = 0; m < 4; ++m) {
                int r = wr * 64 + m * 16 + lr;
                af[m] = *(const f16x8*)&As[swz(r, kk * 64 + lk * 16)];
            }
            #pragma unroll
            for (int n = 0; n < 4; ++n) {
                int r = wc * 64 + n * 16 + lr;
                bf[n] = *(const f16x8*)&Bs[swz(r, kk * 64 + lk * 16)];
            }
            #pragma unroll
            for (int m = 0; m < 4; ++m)
                #pragma unroll
                for (int n = 0; n < 4; ++n)
                    acc[m][n] = __builtin_amdgcn_mfma_f32_16x16x32_f16(
                        af[m], bf[n], acc[m][n], 0, 0, 0);
        }

        if (ks + 1 < NSTEP) write_lds(cur ^ 1);   // other buffer: no pre-barrier needed
        __syncthreads();
        cur ^= 1;
    }

    // Epilogue: C/D layout col = lane&15, row = (lane>>4)*4 + j
    const int cb = col0 + wc * 64;
    const int rb0 = row0 + wr * 64;
    float bv[4];
    #pragma unroll
    for (int n = 0; n < 4; ++n) bv[n] = bias[(size_t)e * ND + cb + n * 16 + lr];
    #pragma unroll
    for (int m = 0; m < 4; ++m) {
        #pragma unroll
        for (int j = 0; j < 4; ++j) {
            int r = rb0 + m * 16 + lk * 4 + j;
            float* yp = Y + (size_t)r * ND + cb + lr;
            #pragma unroll
            for (int n = 0; n < 4; ++n)
                yp[n * 16] = acc[m][n][j] + bv[n];
        }
    }
}

extern "C" void kernel_launch(void* const* d_in, const int* in_sizes, int n_in,
                              void* d_out, int out_size, void* d_ws, size_t ws_size,
                              hipStream_t stream) {
    const float* inp  = (const float*)d_in[0];
    const void*  cnt  = d_in[1];               // int32 or int64, detected in-kernel
    const float* wgt  = (const float*)d_in[2];
    const float* bias = (const float*)d_in[3];
    float* out = (float*)d_out;

    dim3 grid((TT / BM) * (ND / BN));          // 128 * 24 = 3072 blocks
    dim3 block(NTHREADS);
    grouped_gemm_f16<<<grid, block, 0, stream>>>(inp, cnt, wgt, bias, out);
}

// Round 3
// 222.511 us; speedup vs baseline: 1.1415x; 1.1415x over previous
//
#include <hip/hip_runtime.h>

typedef __attribute__((ext_vector_type(8))) _Float16 f16x8;
typedef __attribute__((ext_vector_type(2))) __fp16   fp16x2;  // cvt_pkrtz return type
typedef __attribute__((ext_vector_type(4))) float    f32x4;

#define TT 16384
#define KD 1024
#define ND 3072
#define NE 16

#define BM 256
#define BN 256
#define BK 64
#define NSTEP (KD / BK)   // 16
#define NTHREADS 512
#define ROWB (BK * 2)     // 128 bytes per LDS row (fp16)

// XOR swizzle: spreads same-column reads of 8 consecutive rows across banks.
// (16 rows -> 2-way aliasing, which is free per m136.)
__device__ __forceinline__ int swz(int row, int kbyte) {
    return row * ROWB + (kbyte ^ ((row & 7) << 4));
}

__device__ __forceinline__ int find_expert(const void* cntp, int row0) {
    // JAX default config demotes int64 -> int32; detect which layout we got.
    const int* w = (const int*)cntp;
    int oddsum = 0;
    #pragma unroll
    for (int i = 1; i < 16; i += 2) oddsum |= w[i];
    int e = 0;
    long long cum = 0;
    if (oddsum == 0) {  // int64 counts (high words all zero)
        const long long* c = (const long long*)cntp;
        #pragma unroll
        for (int i = 0; i < NE; ++i) { if ((long long)row0 >= cum) e = i; cum += c[i]; }
    } else {            // int32 counts
        #pragma unroll
        for (int i = 0; i < NE; ++i) { if ((long long)row0 >= cum) e = i; cum += w[i]; }
    }
    return e;
}

__launch_bounds__(NTHREADS, 2)
__global__ void grouped_gemm_f16(const float* __restrict__ A,
                                 const void* __restrict__ cnt,
                                 const float* __restrict__ W,
                                 const float* __restrict__ bias,
                                 float* __restrict__ Y) {
    // [dbuf][A/B][256 rows x 128B] = 128 KiB
    __shared__ __align__(16) char ldsbuf[2][2][BM * ROWB];

    // T1: bijective XCD-aware swizzle (768 % 8 == 0 -> chunks of 96)
    const int nwg = gridDim.x;
    const int bid0 = blockIdx.x;
    const int wgid = (bid0 & 7) * (nwg >> 3) + (bid0 >> 3);

    const int mt = wgid / (ND / BN);
    const int nt = wgid % (ND / BN);
    const int row0 = mt * BM;
    const int col0 = nt * BN;

    const int e = find_expert(cnt, row0);
    const float* We = W + (size_t)e * ND * KD;

    const int tid = threadIdx.x;
    const int lane = tid & 63;
    const int w = tid >> 6;   // wave 0..7
    const int wr = w >> 2;    // 0..1 (M half, 128 rows)
    const int wc = w & 3;     // 0..3 (N quarter, 64 cols)
    const int lr = lane & 15;
    const int lk = lane >> 4;

    // Staging: each tile (A and B) = 256 rows x 64 k fp32 = 2048 chunks of 8
    // floats. 512 threads x 4 chunks each. tid walks k-first (coalesced).
    int soff[4];
    size_t aoff[4], boff[4];
    #pragma unroll
    for (int c = 0; c < 4; ++c) {
        int q = c * NTHREADS + tid;
        int r = q >> 3;
        int kb = (q & 7) * 8;
        soff[c] = swz(r, kb * 2);
        aoff[c] = (size_t)(row0 + r) * KD + kb;
        boff[c] = (size_t)(col0 + r) * KD + kb;
    }

    f32x4 ra[4][2], rb[4][2];   // 64 VGPRs of in-flight staging

    auto load_regs = [&](int ks) {
        const int k0 = ks * BK;
        #pragma unroll
        for (int c = 0; c < 4; ++c) {
            const float* ap = A + aoff[c] + k0;
            ra[c][0] = *(const f32x4*)ap;
            ra[c][1] = *(const f32x4*)(ap + 4);
            const float* bp = We + boff[c] + k0;
            rb[c][0] = *(const f32x4*)bp;
            rb[c][1] = *(const f32x4*)(bp + 4);
        }
    };

    auto write_lds = [&](int buf) {
        #pragma unroll
        for (int c = 0; c < 4; ++c) {
            union { f16x8 v; fp16x2 h[4]; } ua, ub;
            ua.h[0] = __builtin_amdgcn_cvt_pkrtz(ra[c][0][0], ra[c][0][1]);
            ua.h[1] = __builtin_amdgcn_cvt_pkrtz(ra[c][0][2], ra[c][0][3]);
            ua.h[2] = __builtin_amdgcn_cvt_pkrtz(ra[c][1][0], ra[c][1][1]);
            ua.h[3] = __builtin_amdgcn_cvt_pkrtz(ra[c][1][2], ra[c][1][3]);
            ub.h[0] = __builtin_amdgcn_cvt_pkrtz(rb[c][0][0], rb[c][0][1]);
            ub.h[1] = __builtin_amdgcn_cvt_pkrtz(rb[c][0][2], rb[c][0][3]);
            ub.h[2] = __builtin_amdgcn_cvt_pkrtz(rb[c][1][0], rb[c][1][1]);
            ub.h[3] = __builtin_amdgcn_cvt_pkrtz(rb[c][1][2], rb[c][1][3]);
            *(f16x8*)&ldsbuf[buf][0][soff[c]] = ua.v;
            *(f16x8*)&ldsbuf[buf][1][soff[c]] = ub.v;
        }
    };

    f32x4 acc[8][4] = {};   // 128 VGPRs: per-wave 128x64 output

    load_regs(0);
    write_lds(0);
    __syncthreads();

    int cur = 0;
    for (int ks = 0; ks < NSTEP; ++ks) {
        // T14 issue-early: next K-tile's global loads go out before compute;
        // vmcnt drains only at write_lds below, under ~620 cyc of MFMA.
        if (ks + 1 < NSTEP) load_regs(ks + 1);

        const char* As = ldsbuf[cur][0];
        const char* Bs = ldsbuf[cur][1];
        #pragma unroll
        for (int kk = 0; kk < 2; ++kk) {          // two K=32 sub-steps
            f16x8 af[8], bf[4];
            #pragma unroll
            for (int m = 0; m < 8; ++m) {
                int r = wr * 128 + m * 16 + lr;
                af[m] = *(const f16x8*)&As[swz(r, kk * 64 + lk * 16)];
            }
            #pragma unroll
            for (int n = 0; n < 4; ++n) {
                int r = wc * 64 + n * 16 + lr;
                bf[n] = *(const f16x8*)&Bs[swz(r, kk * 64 + lk * 16)];
            }
            #pragma unroll
            for (int m = 0; m < 8; ++m)
                #pragma unroll
                for (int n = 0; n < 4; ++n)
                    acc[m][n] = __builtin_amdgcn_mfma_f32_16x16x32_f16(
                        af[m], bf[n], acc[m][n], 0, 0, 0);
        }

        if (ks + 1 < NSTEP) write_lds(cur ^ 1);   // other buffer: no pre-barrier needed
        __syncthreads();
        cur ^= 1;
    }

    // Epilogue: C/D layout col = lane&15, row = (lane>>4)*4 + j
    const int cb = col0 + wc * 64;
    const int rb0 = row0 + wr * 128;
    float bv[4];
    #pragma unroll
    for (int n = 0; n < 4; ++n) bv[n] = bias[(size_t)e * ND + cb + n * 16 + lr];
    #pragma unroll
    for (int m = 0; m < 8; ++m) {
        #pragma unroll
        for (int j = 0; j < 4; ++j) {
            int r = rb0 + m * 16 + lk * 4 + j;
            float* yp = Y + (size_t)r * ND + cb + lr;
            #pragma unroll
            for (int n = 0; n < 4; ++n)
                yp[n * 16] = acc[m][n][j] + bv[n];
        }
    }
}

extern "C" void kernel_launch(void* const* d_in, const int* in_sizes, int n_in,
                              void* d_out, int out_size, void* d_ws, size_t ws_size,
                              hipStream_t stream) {
    const float* inp  = (const float*)d_in[0];
    const void*  cnt  = d_in[1];               // int32 or int64, detected in-kernel
    const float* wgt  = (const float*)d_in[2];
    const float* bias = (const float*)d_in[3];
    float* out = (float*)d_out;

    dim3 grid((TT / BM) * (ND / BN));          // 64 * 12 = 768 blocks
    dim3 block(NTHREADS);
    grouped_gemm_f16<<<grid, block, 0, stream>>>(inp, cnt, wgt, bias, out);
}